// Round 12
// baseline (451.983 us; speedup 1.0000x reference)
//
#include <hip/hip_runtime.h>

#define N_NODES 100000
#define N_EDGES 800000
#define N_ETYPES 5
#define NUM_GRAPHS 64
#define IN_DIM 23
#define HID_DIM 128
#define OUT_DIM 64
#define N_KEYS (N_NODES * N_ETYPES)      // 500,000  (key = dst*5 + t)
#define KPB 2048                         // keys per bin
#define NBINS ((N_KEYS + KPB - 1) / KPB) // 245
#define BIN_CAP 18432                    // Poisson(16384) + 16 sigma
#define CHUNK 8192                       // edges per k_bin block
#define TOT_EDGES (N_EDGES * N_ETYPES)   // 4,000,000

typedef unsigned short u16;
typedef unsigned int u32;
using short8 = __attribute__((ext_vector_type(8))) short;
using f32x4  = __attribute__((ext_vector_type(4))) float;

__device__ __forceinline__ float bf2f(u16 v) {
    union { unsigned u; float f; } x; x.u = ((unsigned)v) << 16; return x.f;
}
__device__ __forceinline__ float lo2f(u32 v) {
    union { unsigned u; float f; } x; x.u = v << 16; return x.f;
}
__device__ __forceinline__ float hi2f(u32 v) {
    union { unsigned u; float f; } x; x.u = v & 0xffff0000u; return x.f;
}
__device__ __forceinline__ u16 f2bf(float f) {
    union { float f; unsigned u; } x; x.f = f;
    unsigned r = x.u + 0x7fff + ((x.u >> 16) & 1);   // RNE
    return (u16)(r >> 16);
}

// ---------------- prep: W1t/W2t/b1s (bf16, transposed, zero-padded) + xb ----------------
__global__ __launch_bounds__(256) void k_prep(const float* __restrict__ W1,
                                              const float* __restrict__ W2,
                                              const float* __restrict__ b1,
                                              const float* __restrict__ x,
                                              u16* __restrict__ w1t,
                                              u16* __restrict__ w2t,
                                              float* __restrict__ b1s,
                                              u16* __restrict__ xb) {
    int stride = gridDim.x * 256;
    int g0 = blockIdx.x * 256 + threadIdx.x;
    for (int i = g0; i < HID_DIM * 160; i += stride) {       // w1t[hid][k], k=t*32+f
        int hid = i / 160, k = i - hid * 160;
        int t = k >> 5, f = k & 31;
        w1t[i] = (f < IN_DIM) ? f2bf(W1[((size_t)t * IN_DIM + f) * HID_DIM + hid]) : (u16)0;
    }
    for (int i = g0; i < N_ETYPES * OUT_DIM * HID_DIM; i += stride) { // w2t[t][out][k]
        int t = i >> 13, r = i & 8191;
        int out = r >> 7, k = r & 127;
        w2t[i] = f2bf(W2[((size_t)t * HID_DIM + k) * OUT_DIM + out]);
    }
    for (int i = g0; i < HID_DIM; i += stride) {
        float s = 0.f;
        #pragma unroll
        for (int t = 0; t < N_ETYPES; ++t) s += b1[t * HID_DIM + i];
        b1s[i] = s;
    }
    for (int i = g0; i < N_NODES * 32; i += stride) {        // xb padded to 32 cols
        int n = i >> 5, f = i & 31;
        xb[i] = (f < IN_DIM) ? f2bf(x[(size_t)n * IN_DIM + f]) : (u16)0;
    }
}

// ---------------- pass A: bin edges by key>>11, per-wave LDS histograms ----------------
__global__ __launch_bounds__(256) void k_bin(const int* __restrict__ edges,
                                             int* __restrict__ bin_cnt,
                                             int* __restrict__ binned) {
    __shared__ int s_key[CHUNK];      // 32 KB
    __shared__ int s_hist[4][256];    // 4 KB (per-wave)
    __shared__ int s_base[4][256];    // 4 KB (per-wave running offsets)
    int tid = threadIdx.x;
    int w = tid >> 6;
    int g0 = blockIdx.x * CHUNK;
    int nch = TOT_EDGES - g0; if (nch > CHUNK) nch = CHUNK;
    for (int i = tid; i < 4 * 256; i += 256) ((int*)s_hist)[i] = 0;
    __syncthreads();
    // sweep 1: read dst, per-wave histogram, stash keys
    for (int i = tid; i < nch; i += 256) {
        int gi = g0 + i;
        int t = (unsigned)gi / (unsigned)N_EDGES;          // const divisor -> magic mul
        int e = gi - t * N_EDGES;
        int dst = edges[((size_t)t * 2 + 1) * N_EDGES + e];
        int key = dst * N_ETYPES + t;
        s_key[i] = key;
        atomicAdd(&s_hist[w][key >> 11], 1);
    }
    __syncthreads();
    // reserve: one global atomic per non-empty (block, bin); per-wave sub-bases
    for (int i = tid; i < NBINS; i += 256) {
        int h0 = s_hist[0][i], h1 = s_hist[1][i], h2 = s_hist[2][i], h3 = s_hist[3][i];
        int h = h0 + h1 + h2 + h3;
        int base = h ? atomicAdd(&bin_cnt[i], h) : 0;
        s_base[0][i] = base;
        s_base[1][i] = base + h0;
        s_base[2][i] = base + h0 + h1;
        s_base[3][i] = base + h0 + h1 + h2;
    }
    __syncthreads();
    // sweep 2: read src, place entries (same thread -> same edges as sweep 1)
    for (int i = tid; i < nch; i += 256) {
        int gi = g0 + i;
        int t = (unsigned)gi / (unsigned)N_EDGES;
        int e = gi - t * N_EDGES;
        int src = edges[((size_t)t * 2 + 0) * N_EDGES + e];
        int key = s_key[i];
        int bin = key >> 11;
        int pos = atomicAdd(&s_base[w][bin], 1);
        if (pos < BIN_CAP)
            binned[(size_t)bin * BIN_CAP + pos] = ((key & 2047) << 17) | src;
    }
}

// ---------------- pass B: per-bin counting sort -> rowptr + CSR ----------------
__global__ __launch_bounds__(256) void k_csr(const int* __restrict__ bin_cnt,
                                             const int* __restrict__ binned,
                                             int* __restrict__ rowptr,
                                             int* __restrict__ csr) {
    __shared__ int s_cnt[KPB];        // 8 KB
    __shared__ int s_ofs[KPB];        // 8 KB
    __shared__ int s_red[256];
    int tid = threadIdx.x;
    int b = blockIdx.x;
    // csr_base = sum bin_cnt[0..b)
    int ps = 0;
    for (int i = tid; i < b; i += 256) ps += bin_cnt[i];
    s_red[tid] = ps;
    __syncthreads();
    for (int s = 128; s > 0; s >>= 1) {
        if (tid < s) s_red[tid] += s_red[tid + s];
        __syncthreads();
    }
    int csr_base = s_red[0];
    __syncthreads();
    int cnt_b = bin_cnt[b];
    if (cnt_b > BIN_CAP) cnt_b = BIN_CAP;
    int key0 = b * KPB;
    int keys_in = N_KEYS - key0; if (keys_in > KPB) keys_in = KPB;
    for (int i = tid; i < KPB; i += 256) s_cnt[i] = 0;
    __syncthreads();
    const int* ep = binned + (size_t)b * BIN_CAP;
    for (int i = tid; i < cnt_b; i += 256)
        atomicAdd(&s_cnt[ep[i] >> 17], 1);
    __syncthreads();
    // exclusive scan over 2048 counters: 8/thread serial + block Hillis-Steele
    int loc[8]; int base_t = 0;
    #pragma unroll
    for (int q = 0; q < 8; ++q) { loc[q] = base_t; base_t += s_cnt[tid * 8 + q]; }
    s_red[tid] = base_t;
    __syncthreads();
    for (int s = 1; s < 256; s <<= 1) {
        int add = (tid >= s) ? s_red[tid - s] : 0;
        __syncthreads();
        s_red[tid] += add;
        __syncthreads();
    }
    int excl = (tid == 0) ? 0 : s_red[tid - 1];
    #pragma unroll
    for (int q = 0; q < 8; ++q) {
        int k = tid * 8 + q;
        int o = excl + loc[q];
        s_ofs[k] = o;
        if (k < keys_in) rowptr[key0 + k] = csr_base + o;
    }
    if (b == NBINS - 1 && tid == 0) rowptr[N_KEYS] = csr_base + cnt_b;
    __syncthreads();
    // scatter into CSR (writes land in a 64KB L2-hot window)
    for (int i = tid; i < cnt_b; i += 256) {
        int entry = ep[i];
        int pos = atomicAdd(&s_ofs[entry >> 17], 1);
        csr[csr_base + pos] = entry & 0x1FFFF;
    }
}

// ------ layer-1 gather: 32-lane group per (node,etype); 8 lanes x 8B cover a row,
// ------ sub = lane>>3 processes every 4th neighbor. All __shfl are in UNIFORM control
// ------ flow (kend = kmax rounded up to 4 makes trip counts lane-invariant); only the
// ------ dependent loads/adds are predicated on k < kmax.
__global__ __launch_bounds__(256) void k_gather1(const int* __restrict__ rowptr,
                                                 const int* __restrict__ csr,
                                                 const u32* __restrict__ xb32,
                                                 u32* __restrict__ acat32) {
    int tid = threadIdx.x;
    int lane = tid & 31;
    int fl = lane & 7;                        // u32 cols 2*fl, 2*fl+1
    int sub = lane >> 3;                      // 0..3
    int lanebase = tid & 32;                  // group base within 64-lane wave
    int n = blockIdx.x * 8 + (tid >> 5);
    int t = blockIdx.y;
    int key = n * N_ETYPES + t;
    int rp0 = rowptr[key];
    int deg = rowptr[key + 1] - rp0;
    int stage = csr[rp0 + lane];              // 32 staged entries (csr padded)
    int kmax = deg < 32 ? deg : 32;
    int kend = (kmax + 3) & ~3;               // group-uniform, multiple of 4
    float a0 = 0.f, a1 = 0.f, a2 = 0.f, a3 = 0.f;
    if (sub == 0) {                           // gcn self term, counted once
        u32 v0 = xb32[(size_t)n * 16 + fl * 2];
        u32 v1 = xb32[(size_t)n * 16 + fl * 2 + 1];
        a0 = lo2f(v0); a1 = hi2f(v0); a2 = lo2f(v1); a3 = hi2f(v1);
    }
    int k = sub;
    for (; k + 4 < kend; k += 8) {            // uniform trips; shfl unconditional
        int sA = __shfl(stage, lanebase + k);
        int sB = __shfl(stage, lanebase + k + 4);
        if (k < kmax) {
            u32 vA0 = xb32[(size_t)sA * 16 + fl * 2];
            u32 vA1 = xb32[(size_t)sA * 16 + fl * 2 + 1];
            a0 += lo2f(vA0); a1 += hi2f(vA0);
            a2 += lo2f(vA1); a3 += hi2f(vA1);
        }
        if (k + 4 < kmax) {
            u32 vB0 = xb32[(size_t)sB * 16 + fl * 2];
            u32 vB1 = xb32[(size_t)sB * 16 + fl * 2 + 1];
            a0 += lo2f(vB0); a1 += hi2f(vB0);
            a2 += lo2f(vB1); a3 += hi2f(vB1);
        }
    }
    if (k < kend) {                           // uniform activity (kend mult of 4)
        int sA = __shfl(stage, lanebase + k);
        if (k < kmax) {
            u32 vA0 = xb32[(size_t)sA * 16 + fl * 2];
            u32 vA1 = xb32[(size_t)sA * 16 + fl * 2 + 1];
            a0 += lo2f(vA0); a1 += hi2f(vA0);
            a2 += lo2f(vA1); a3 += hi2f(vA1);
        }
    }
    for (int kk = 32 + sub; kk < deg; kk += 4) {  // deg>32: ~never; plain global loads
        int sA = csr[rp0 + kk];
        u32 vA0 = xb32[(size_t)sA * 16 + fl * 2];
        u32 vA1 = xb32[(size_t)sA * 16 + fl * 2 + 1];
        a0 += lo2f(vA0); a1 += hi2f(vA0);
        a2 += lo2f(vA1); a3 += hi2f(vA1);
    }
    // fold subs 1..3 into sub 0 (uniform; xor within the 32-lane group)
    a0 += __shfl_xor(a0, 8);  a1 += __shfl_xor(a1, 8);
    a2 += __shfl_xor(a2, 8);  a3 += __shfl_xor(a3, 8);
    a0 += __shfl_xor(a0, 16); a1 += __shfl_xor(a1, 16);
    a2 += __shfl_xor(a2, 16); a3 += __shfl_xor(a3, 16);
    if (sub == 0 && fl < 6) {
        float inv = 1.0f / (float)(deg + 1);
        uint2 o;
        o.x = (u32)f2bf(a0 * inv) | ((u32)f2bf(a1 * inv) << 16);
        o.y = (u32)f2bf(a2 * inv) | ((u32)f2bf(a3 * inv) << 16);
        *(uint2*)&acat32[(size_t)n * 60 + t * 12 + fl * 2] = o;
    }
}

// ---------------- fused GEMM chain: acat -> MFMA L1+relu (LDS) -> MFMA L2 -> g -------------
__global__ __launch_bounds__(256) void k_gemm12(const u16* __restrict__ acat,
                                                const u16* __restrict__ w1t,
                                                const u16* __restrict__ w2t,
                                                const float* __restrict__ b1s,
                                                u16* __restrict__ g,
                                                int gt0, int gt1) {
    __shared__ u16 s_a[64 * 168];     // [64][160+8]  21504 B  (reused as s_out)
    __shared__ u16 s_h1[64 * 136];    // [64][128+8]  17408 B
    u16* s_out = s_a;                 // dead after A-frags are in registers
    int tid = threadIdx.x;
    int base = blockIdx.x * 64;

    // stage acat tile: expand [120] packed -> [160] zero-padded (coalesced ushort4)
    for (int i = tid; i < 64 * 40; i += 256) {
        int r = i / 40, col4 = i - r * 40;
        int t = col4 >> 3, q4 = col4 & 7;
        ushort4 v = {0, 0, 0, 0};
        if (q4 < 6 && base + r < N_NODES)
            v = *(const ushort4*)&acat[(size_t)(base + r) * 120 + t * 24 + q4 * 4];
        *(ushort4*)&s_a[r * 168 + t * 32 + q4 * 4] = v;
    }
    __syncthreads();

    int l = tid & 63, w = tid >> 6;
    int lr = l & 15, lg = l >> 4;

    // ---- L1: h1 = relu(s_a @ W1t + b1s) ----
    short8 a5[5];
    #pragma unroll
    for (int ks = 0; ks < 5; ++ks)
        a5[ks] = *(const short8*)&s_a[(w * 16 + lr) * 168 + ks * 32 + lg * 8];
    {
        f32x4 acc[8];
        #pragma unroll
        for (int nt = 0; nt < 8; ++nt) acc[nt] = (f32x4){0.f, 0.f, 0.f, 0.f};
        #pragma unroll
        for (int nt = 0; nt < 8; ++nt) {
            #pragma unroll
            for (int ks = 0; ks < 5; ++ks) {
                short8 b = *(const short8*)&w1t[(nt * 16 + lr) * 160 + ks * 32 + lg * 8];
                acc[nt] = __builtin_amdgcn_mfma_f32_16x16x32_bf16(a5[ks], b, acc[nt], 0, 0, 0);
            }
        }
        #pragma unroll
        for (int nt = 0; nt < 8; ++nt) {
            float bias = b1s[nt * 16 + lr];
            #pragma unroll
            for (int r = 0; r < 4; ++r) {
                float h = acc[nt][r] + bias;
                s_h1[(w * 16 + lg * 4 + r) * 136 + nt * 16 + lr] = f2bf(h > 0.f ? h : 0.f);
            }
        }
    }
    __syncthreads();

    // ---- L2: per etype, g_t = h1 @ W2t ----
    short8 a2[4];
    #pragma unroll
    for (int ks = 0; ks < 4; ++ks)
        a2[ks] = *(const short8*)&s_h1[(w * 16 + lr) * 136 + ks * 32 + lg * 8];
    for (int t = gt0; t < gt1; ++t) {
        f32x4 acc2[4];
        #pragma unroll
        for (int nt = 0; nt < 4; ++nt) acc2[nt] = (f32x4){0.f, 0.f, 0.f, 0.f};
        #pragma unroll
        for (int nt = 0; nt < 4; ++nt) {
            #pragma unroll
            for (int ks = 0; ks < 4; ++ks) {
                short8 b = *(const short8*)&w2t[((size_t)t * OUT_DIM + nt * 16 + lr) * HID_DIM + ks * 32 + lg * 8];
                acc2[nt] = __builtin_amdgcn_mfma_f32_16x16x32_bf16(a2[ks], b, acc2[nt], 0, 0, 0);
            }
        }
        __syncthreads();          // prev s_out consumers done
        #pragma unroll
        for (int nt = 0; nt < 4; ++nt)
            #pragma unroll
            for (int r = 0; r < 4; ++r)
                s_out[(w * 16 + lg * 4 + r) * 72 + nt * 16 + lr] = f2bf(acc2[nt][r]);
        __syncthreads();
        size_t pb = (size_t)(t - gt0) * N_NODES;
        #pragma unroll
        for (int j = 0; j < 4; ++j) {
            int flat = j * 256 + tid;
            int rrow = flat >> 4, c4 = (flat & 15) * 4;
            int n = base + rrow;
            if (n < N_NODES)
                *(ushort4*)&g[(pb + n) * OUT_DIM + c4] = *(const ushort4*)&s_out[rrow * 72 + c4];
        }
    }
}

// ------ layer-2 gather: full 64-lane wave per node; 16 lanes x 8B cover a row,
// ------ sub = lane>>4 processes every 4th neighbor. Same uniform-shfl discipline.
__global__ __launch_bounds__(256) void k_gather2(const int* __restrict__ rowptr,
                                                 const int* __restrict__ csr,
                                                 const u32* __restrict__ g32,
                                                 u32* __restrict__ h232) {
    int tid = threadIdx.x;
    int lane = tid & 63;
    int fl = lane & 15;                       // u32 cols 2*fl, 2*fl+1
    int sub = lane >> 4;                      // 0..3
    int n = blockIdx.x * 4 + (tid >> 6);
    int kb = n * N_ETYPES;
    float acc0 = 0.f, acc1 = 0.f, acc2 = 0.f, acc3 = 0.f;
    for (int tc = 0; tc < N_ETYPES; ++tc) {
        int rp0 = rowptr[kb + tc];
        int deg = rowptr[kb + tc + 1] - rp0;
        int stage = csr[rp0 + lane];          // 64 staged entries
        int kmax = deg < 64 ? deg : 64;
        int kend = (kmax + 3) & ~3;           // wave-uniform, multiple of 4
        const u32* gp = g32 + (size_t)tc * N_NODES * 32;
        float s0 = 0.f, s1 = 0.f, s2 = 0.f, s3 = 0.f;
        if (sub == 0) {                       // self
            u32 v0 = gp[(size_t)n * 32 + fl * 2];
            u32 v1 = gp[(size_t)n * 32 + fl * 2 + 1];
            s0 = lo2f(v0); s1 = hi2f(v0); s2 = lo2f(v1); s3 = hi2f(v1);
        }
        int k = sub;
        for (; k + 4 < kend; k += 8) {        // uniform trips; shfl unconditional
            int pA = __shfl(stage, k);
            int pB = __shfl(stage, k + 4);
            if (k < kmax) {
                u32 vA0 = gp[(size_t)pA * 32 + fl * 2];
                u32 vA1 = gp[(size_t)pA * 32 + fl * 2 + 1];
                s0 += lo2f(vA0); s1 += hi2f(vA0);
                s2 += lo2f(vA1); s3 += hi2f(vA1);
            }
            if (k + 4 < kmax) {
                u32 vB0 = gp[(size_t)pB * 32 + fl * 2];
                u32 vB1 = gp[(size_t)pB * 32 + fl * 2 + 1];
                s0 += lo2f(vB0); s1 += hi2f(vB0);
                s2 += lo2f(vB1); s3 += hi2f(vB1);
            }
        }
        if (k < kend) {                       // uniform activity
            int pA = __shfl(stage, k);
            if (k < kmax) {
                u32 vA0 = gp[(size_t)pA * 32 + fl * 2];
                u32 vA1 = gp[(size_t)pA * 32 + fl * 2 + 1];
                s0 += lo2f(vA0); s1 += hi2f(vA0);
                s2 += lo2f(vA1); s3 += hi2f(vA1);
            }
        }
        for (int kk = 64 + sub; kk < deg; kk += 4) {  // deg>64: ~never; global loads
            int pA = csr[rp0 + kk];
            u32 vA0 = gp[(size_t)pA * 32 + fl * 2];
            u32 vA1 = gp[(size_t)pA * 32 + fl * 2 + 1];
            s0 += lo2f(vA0); s1 += hi2f(vA0);
            s2 += lo2f(vA1); s3 += hi2f(vA1);
        }
        float inv = 1.0f / (float)(deg + 1);
        acc0 += s0 * inv; acc1 += s1 * inv;
        acc2 += s2 * inv; acc3 += s3 * inv;
    }
    // fold subs 1..3 into sub 0 (uniform; inv already applied)
    acc0 += __shfl_xor(acc0, 16); acc1 += __shfl_xor(acc1, 16);
    acc2 += __shfl_xor(acc2, 16); acc3 += __shfl_xor(acc3, 16);
    acc0 += __shfl_xor(acc0, 32); acc1 += __shfl_xor(acc1, 32);
    acc2 += __shfl_xor(acc2, 32); acc3 += __shfl_xor(acc3, 32);
    if (sub == 0) {
        uint2 o;
        o.x = (u32)f2bf(acc0) | ((u32)f2bf(acc1) << 16);
        o.y = (u32)f2bf(acc2) | ((u32)f2bf(acc3) << 16);
        *(uint2*)&h232[(size_t)n * 32 + fl * 2] = o;
    }
}

// ---------------- pooling stage 1: chunked partial sums (sorted gids -> few atomics) -------
__global__ __launch_bounds__(256) void k_pool1(const u16* __restrict__ h2,
                                               const int* __restrict__ gids,
                                               float* __restrict__ out_acc) {
    int w = threadIdx.x >> 6, lane = threadIdx.x & 63;
    int n0 = blockIdx.x * 256 + w * 64;
    int nend = n0 + 64; if (nend > N_NODES) nend = N_NODES;
    float acc = 0.f;
    int cur = -1;
    for (int n = n0; n < nend; ++n) {
        int gid = gids[n];
        if (gid != cur) {
            if (cur >= 0) atomicAdd(&out_acc[cur * OUT_DIM + lane], acc);
            acc = 0.f; cur = gid;
        }
        acc += bf2f(h2[(size_t)n * OUT_DIM + lane]);
    }
    if (cur >= 0) atomicAdd(&out_acc[cur * OUT_DIM + lane], acc);
}

// ---------------- pooling stage 2: divide by count, add bias ----------------
__global__ __launch_bounds__(64) void k_pool2(const float* __restrict__ out_acc,
                                              const int* __restrict__ gids,
                                              const float* __restrict__ b2,
                                              float* __restrict__ out) {
    int gid = blockIdx.x, j = threadIdx.x;
    int lo = 0, hi = N_NODES;
    while (lo < hi) { int mid = (lo + hi) >> 1; if (gids[mid] < gid) lo = mid + 1; else hi = mid; }
    int start = lo;
    hi = N_NODES;
    while (lo < hi) { int mid = (lo + hi) >> 1; if (gids[mid] < gid + 1) lo = mid + 1; else hi = mid; }
    int count = lo - start;
    float b = 0.f;
    #pragma unroll
    for (int t = 0; t < N_ETYPES; ++t) b += b2[t * OUT_DIM + j];
    float c = (float)count;
    out[gid * OUT_DIM + j] = (out_acc[gid * OUT_DIM + j] + c * b) / fmaxf(c, 1.0f);
}

extern "C" void kernel_launch(void* const* d_in, const int* in_sizes, int n_in,
                              void* d_out, int out_size, void* d_ws, size_t ws_size,
                              hipStream_t stream) {
    const float* x    = (const float*)d_in[0];
    const int*   edges= (const int*)d_in[1];
    const int*   gids = (const int*)d_in[2];
    const float* W1   = (const float*)d_in[3];
    const float* b1   = (const float*)d_in[4];
    const float* W2   = (const float*)d_in[5];
    const float* b2   = (const float*)d_in[6];
    float* out = (float*)d_out;

    // word-offset (u32) workspace layout; total 31,335,296 words = 125.3 MB (audited r10)
    int*   bin_cnt = (int*)d_ws;                          // 0       (256)
    int*   rowptr  = bin_cnt + 256;                       // 256     (500,016)
    int*   csr     = bin_cnt + 500272;                    // 500,272 (4,000,080)
    u16*   xb      = (u16*)(bin_cnt + 4500352);           // 4,500,352 (1,600,000 u16 = 800,000 w)
    u16*   w1t     = (u16*)(bin_cnt + 6100352);           // 6,100,352 (20,480 u16 = 10,240 w)
    u16*   w2t     = (u16*)(bin_cnt + 6110592);           // 6,110,592 (40,960 u16 = 20,480 w)
    float* b1s     = (float*)(bin_cnt + 6131072);         // 6,131,072 (128, pad to 6,131,200)
    u16*   acat    = (u16*)(bin_cnt + 6131200);           // 6,131,200 (12,000,000 u16 = 6,000,000 w)
    u16*   g       = (u16*)(bin_cnt + 12131200);          // 12,131,200 (32,000,000 u16 = 16,000,000 w)
    int*   binned  = bin_cnt + 12131200;                  // alias over g head (4,515,840 w)
    u16*   h2      = (u16*)(bin_cnt + 28131200);          // 28,131,200 (6,400,000 u16 = 3,200,000 w)
    float* out_acc = (float*)(bin_cnt + 31331200);        // 31,331,200 (4,096)

    hipMemsetAsync(bin_cnt, 0, 256 * sizeof(int), stream);
    hipMemsetAsync(out_acc, 0, NUM_GRAPHS * OUT_DIM * sizeof(float), stream);

    k_prep<<<1024, 256, 0, stream>>>(W1, W2, b1, x, w1t, w2t, b1s, xb);
    k_bin<<<(TOT_EDGES + CHUNK - 1) / CHUNK, 256, 0, stream>>>(edges, bin_cnt, binned);
    k_csr<<<NBINS, 256, 0, stream>>>(bin_cnt, binned, rowptr, csr);

    k_gather1<<<dim3(N_NODES / 8, N_ETYPES), 256, 0, stream>>>(
        rowptr, csr, (const u32*)xb, (u32*)acat);

    int nblk = (N_NODES + 63) / 64;
    k_gemm12<<<nblk, 256, 0, stream>>>(acat, w1t, w2t, b1s, g, 0, 5);   // single pass, 5 planes
    k_gather2<<<N_NODES / 4, 256, 0, stream>>>(rowptr, csr, (const u32*)g, (u32*)h2);

    k_pool1<<<(N_NODES + 255) / 256, 256, 0, stream>>>(h2, gids, out_acc);
    k_pool2<<<NUM_GRAPHS, 64, 0, stream>>>(out_acc, gids, b2, out);
}

// Round 13
// 411.473 us; speedup vs baseline: 1.0985x; 1.0985x over previous
//
#include <hip/hip_runtime.h>

#define N_NODES 100000
#define N_EDGES 800000
#define N_ETYPES 5
#define NUM_GRAPHS 64
#define IN_DIM 23
#define HID_DIM 128
#define OUT_DIM 64
#define N_KEYS (N_NODES * N_ETYPES)      // 500,000  (key = dst*5 + t)
#define KPB 2048                         // keys per bin
#define NBINS ((N_KEYS + KPB - 1) / KPB) // 245
#define BIN_CAP 18432                    // Poisson(16384) + 16 sigma
#define CHUNK 8192                       // edges per k_bin block
#define TOT_EDGES (N_EDGES * N_ETYPES)   // 4,000,000

typedef unsigned short u16;
typedef unsigned int u32;
using short8 = __attribute__((ext_vector_type(8))) short;
using f32x4  = __attribute__((ext_vector_type(4))) float;

__device__ __forceinline__ float bf2f(u16 v) {
    union { unsigned u; float f; } x; x.u = ((unsigned)v) << 16; return x.f;
}
__device__ __forceinline__ float lo2f(u32 v) {
    union { unsigned u; float f; } x; x.u = v << 16; return x.f;
}
__device__ __forceinline__ float hi2f(u32 v) {
    union { unsigned u; float f; } x; x.u = v & 0xffff0000u; return x.f;
}
__device__ __forceinline__ u16 f2bf(float f) {
    union { float f; unsigned u; } x; x.f = f;
    unsigned r = x.u + 0x7fff + ((x.u >> 16) & 1);   // RNE
    return (u16)(r >> 16);
}

// ---------------- prep: W1t/W2t/b1s (bf16, transposed, zero-padded) + xb ----------------
__global__ __launch_bounds__(256) void k_prep(const float* __restrict__ W1,
                                              const float* __restrict__ W2,
                                              const float* __restrict__ b1,
                                              const float* __restrict__ x,
                                              u16* __restrict__ w1t,
                                              u16* __restrict__ w2t,
                                              float* __restrict__ b1s,
                                              u16* __restrict__ xb) {
    int stride = gridDim.x * 256;
    int g0 = blockIdx.x * 256 + threadIdx.x;
    for (int i = g0; i < HID_DIM * 160; i += stride) {       // w1t[hid][k], k=t*32+f
        int hid = i / 160, k = i - hid * 160;
        int t = k >> 5, f = k & 31;
        w1t[i] = (f < IN_DIM) ? f2bf(W1[((size_t)t * IN_DIM + f) * HID_DIM + hid]) : (u16)0;
    }
    for (int i = g0; i < N_ETYPES * OUT_DIM * HID_DIM; i += stride) { // w2t[t][out][k]
        int t = i >> 13, r = i & 8191;
        int out = r >> 7, k = r & 127;
        w2t[i] = f2bf(W2[((size_t)t * HID_DIM + k) * OUT_DIM + out]);
    }
    for (int i = g0; i < HID_DIM; i += stride) {
        float s = 0.f;
        #pragma unroll
        for (int t = 0; t < N_ETYPES; ++t) s += b1[t * HID_DIM + i];
        b1s[i] = s;
    }
    for (int i = g0; i < N_NODES * 32; i += stride) {        // xb padded to 32 cols
        int n = i >> 5, f = i & 31;
        xb[i] = (f < IN_DIM) ? f2bf(x[(size_t)n * IN_DIM + f]) : (u16)0;
    }
}

// ---------------- pass A: bin edges by key>>11, per-wave LDS histograms ----------------
__global__ __launch_bounds__(256) void k_bin(const int* __restrict__ edges,
                                             int* __restrict__ bin_cnt,
                                             int* __restrict__ binned) {
    __shared__ int s_key[CHUNK];      // 32 KB
    __shared__ int s_hist[4][256];    // 4 KB (per-wave)
    __shared__ int s_base[4][256];    // 4 KB (per-wave running offsets)
    int tid = threadIdx.x;
    int w = tid >> 6;
    int g0 = blockIdx.x * CHUNK;
    int nch = TOT_EDGES - g0; if (nch > CHUNK) nch = CHUNK;
    for (int i = tid; i < 4 * 256; i += 256) ((int*)s_hist)[i] = 0;
    __syncthreads();
    // sweep 1: read dst, per-wave histogram, stash keys
    for (int i = tid; i < nch; i += 256) {
        int gi = g0 + i;
        int t = (unsigned)gi / (unsigned)N_EDGES;          // const divisor -> magic mul
        int e = gi - t * N_EDGES;
        int dst = edges[((size_t)t * 2 + 1) * N_EDGES + e];
        int key = dst * N_ETYPES + t;
        s_key[i] = key;
        atomicAdd(&s_hist[w][key >> 11], 1);
    }
    __syncthreads();
    // reserve: one global atomic per non-empty (block, bin); per-wave sub-bases
    for (int i = tid; i < NBINS; i += 256) {
        int h0 = s_hist[0][i], h1 = s_hist[1][i], h2 = s_hist[2][i], h3 = s_hist[3][i];
        int h = h0 + h1 + h2 + h3;
        int base = h ? atomicAdd(&bin_cnt[i], h) : 0;
        s_base[0][i] = base;
        s_base[1][i] = base + h0;
        s_base[2][i] = base + h0 + h1;
        s_base[3][i] = base + h0 + h1 + h2;
    }
    __syncthreads();
    // sweep 2: read src, place entries (same thread -> same edges as sweep 1)
    for (int i = tid; i < nch; i += 256) {
        int gi = g0 + i;
        int t = (unsigned)gi / (unsigned)N_EDGES;
        int e = gi - t * N_EDGES;
        int src = edges[((size_t)t * 2 + 0) * N_EDGES + e];
        int key = s_key[i];
        int bin = key >> 11;
        int pos = atomicAdd(&s_base[w][bin], 1);
        if (pos < BIN_CAP)
            binned[(size_t)bin * BIN_CAP + pos] = ((key & 2047) << 17) | src;
    }
}

// ---------------- pass B: per-bin counting sort -> rowptr + CSR ----------------
__global__ __launch_bounds__(256) void k_csr(const int* __restrict__ bin_cnt,
                                             const int* __restrict__ binned,
                                             int* __restrict__ rowptr,
                                             int* __restrict__ csr) {
    __shared__ int s_cnt[KPB];        // 8 KB
    __shared__ int s_ofs[KPB];        // 8 KB
    __shared__ int s_red[256];
    int tid = threadIdx.x;
    int b = blockIdx.x;
    // csr_base = sum bin_cnt[0..b)
    int ps = 0;
    for (int i = tid; i < b; i += 256) ps += bin_cnt[i];
    s_red[tid] = ps;
    __syncthreads();
    for (int s = 128; s > 0; s >>= 1) {
        if (tid < s) s_red[tid] += s_red[tid + s];
        __syncthreads();
    }
    int csr_base = s_red[0];
    __syncthreads();
    int cnt_b = bin_cnt[b];
    if (cnt_b > BIN_CAP) cnt_b = BIN_CAP;
    int key0 = b * KPB;
    int keys_in = N_KEYS - key0; if (keys_in > KPB) keys_in = KPB;
    for (int i = tid; i < KPB; i += 256) s_cnt[i] = 0;
    __syncthreads();
    const int* ep = binned + (size_t)b * BIN_CAP;
    for (int i = tid; i < cnt_b; i += 256)
        atomicAdd(&s_cnt[ep[i] >> 17], 1);
    __syncthreads();
    // exclusive scan over 2048 counters: 8/thread serial + block Hillis-Steele
    int loc[8]; int base_t = 0;
    #pragma unroll
    for (int q = 0; q < 8; ++q) { loc[q] = base_t; base_t += s_cnt[tid * 8 + q]; }
    s_red[tid] = base_t;
    __syncthreads();
    for (int s = 1; s < 256; s <<= 1) {
        int add = (tid >= s) ? s_red[tid - s] : 0;
        __syncthreads();
        s_red[tid] += add;
        __syncthreads();
    }
    int excl = (tid == 0) ? 0 : s_red[tid - 1];
    #pragma unroll
    for (int q = 0; q < 8; ++q) {
        int k = tid * 8 + q;
        int o = excl + loc[q];
        s_ofs[k] = o;
        if (k < keys_in) rowptr[key0 + k] = csr_base + o;
    }
    if (b == NBINS - 1 && tid == 0) rowptr[N_KEYS] = csr_base + cnt_b;
    __syncthreads();
    // scatter into CSR (writes land in a 64KB L2-hot window)
    for (int i = tid; i < cnt_b; i += 256) {
        int entry = ep[i];
        int pos = atomicAdd(&s_ofs[entry >> 17], 1);
        csr[csr_base + pos] = entry & 0x1FFFF;
    }
}

// ------ layer-1 gather: 16-lane group per (node,etype), u32-packed feats, 4-way unroll.
// ------ kmax is group-uniform => all trip counts lane-invariant; shfl never divergent.
__global__ __launch_bounds__(256) void k_gather1(const int* __restrict__ rowptr,
                                                 const int* __restrict__ csr,
                                                 const u32* __restrict__ xb32,
                                                 u32* __restrict__ acat32) {
    int tid = threadIdx.x;
    int lane = tid & 15;
    int lanebase = tid & 48;                  // group base within the 64-lane wave
    int n = blockIdx.x * 16 + (tid >> 4);
    int t = blockIdx.y;
    int key = n * N_ETYPES + t;
    int rp0 = rowptr[key];
    int deg = rowptr[key + 1] - rp0;
    int stage = csr[rp0 + lane];              // 16 staged entries (csr padded)
    int kmax = deg < 16 ? deg : 16;
    u32 v = xb32[(size_t)n * 16 + lane];      // self; pad cols are zero
    float acc0 = lo2f(v), acc1 = hi2f(v);
    float a00 = 0.f, a01 = 0.f, a10 = 0.f, a11 = 0.f;
    float a20 = 0.f, a21 = 0.f, a30 = 0.f, a31 = 0.f;
    int k = 0;
    for (; k + 3 < kmax; k += 4) {            // 4 rows in flight
        int s0 = __shfl(stage, lanebase + k);
        int s1 = __shfl(stage, lanebase + k + 1);
        int s2 = __shfl(stage, lanebase + k + 2);
        int s3 = __shfl(stage, lanebase + k + 3);
        u32 v0 = xb32[(size_t)s0 * 16 + lane];
        u32 v1 = xb32[(size_t)s1 * 16 + lane];
        u32 v2 = xb32[(size_t)s2 * 16 + lane];
        u32 v3 = xb32[(size_t)s3 * 16 + lane];
        a00 += lo2f(v0); a01 += hi2f(v0);
        a10 += lo2f(v1); a11 += hi2f(v1);
        a20 += lo2f(v2); a21 += hi2f(v2);
        a30 += lo2f(v3); a31 += hi2f(v3);
    }
    for (; k < kmax; ++k) {                   // remainder: uniform single steps
        int s0 = __shfl(stage, lanebase + k);
        u32 v0 = xb32[(size_t)s0 * 16 + lane];
        a00 += lo2f(v0); a01 += hi2f(v0);
    }
    for (; k < deg; ++k) {                    // deg>16: rare; uniform broadcast loads
        int s0 = csr[rp0 + k];
        u32 v0 = xb32[(size_t)s0 * 16 + lane];
        a00 += lo2f(v0); a01 += hi2f(v0);
    }
    acc0 += (a00 + a10) + (a20 + a30);
    acc1 += (a01 + a11) + (a21 + a31);
    float inv = 1.0f / (float)(deg + 1);
    if (lane < 12)
        acat32[(size_t)n * 60 + t * 12 + lane] =
            (u32)f2bf(acc0 * inv) | ((u32)f2bf(acc1 * inv) << 16);
}

// ---------------- fused GEMM chain: acat -> MFMA L1+relu (LDS) -> MFMA L2 -> g -------------
__global__ __launch_bounds__(256) void k_gemm12(const u16* __restrict__ acat,
                                                const u16* __restrict__ w1t,
                                                const u16* __restrict__ w2t,
                                                const float* __restrict__ b1s,
                                                u16* __restrict__ g,
                                                int gt0, int gt1) {
    __shared__ u16 s_a[64 * 168];     // [64][160+8]  21504 B  (reused as s_out)
    __shared__ u16 s_h1[64 * 136];    // [64][128+8]  17408 B
    u16* s_out = s_a;                 // dead after A-frags are in registers
    int tid = threadIdx.x;
    int base = blockIdx.x * 64;

    // stage acat tile: expand [120] packed -> [160] zero-padded (coalesced ushort4)
    for (int i = tid; i < 64 * 40; i += 256) {
        int r = i / 40, col4 = i - r * 40;
        int t = col4 >> 3, q4 = col4 & 7;
        ushort4 v = {0, 0, 0, 0};
        if (q4 < 6 && base + r < N_NODES)
            v = *(const ushort4*)&acat[(size_t)(base + r) * 120 + t * 24 + q4 * 4];
        *(ushort4*)&s_a[r * 168 + t * 32 + q4 * 4] = v;
    }
    __syncthreads();

    int l = tid & 63, w = tid >> 6;
    int lr = l & 15, lg = l >> 4;

    // ---- L1: h1 = relu(s_a @ W1t + b1s) ----
    short8 a5[5];
    #pragma unroll
    for (int ks = 0; ks < 5; ++ks)
        a5[ks] = *(const short8*)&s_a[(w * 16 + lr) * 168 + ks * 32 + lg * 8];
    {
        f32x4 acc[8];
        #pragma unroll
        for (int nt = 0; nt < 8; ++nt) acc[nt] = (f32x4){0.f, 0.f, 0.f, 0.f};
        #pragma unroll
        for (int nt = 0; nt < 8; ++nt) {
            #pragma unroll
            for (int ks = 0; ks < 5; ++ks) {
                short8 b = *(const short8*)&w1t[(nt * 16 + lr) * 160 + ks * 32 + lg * 8];
                acc[nt] = __builtin_amdgcn_mfma_f32_16x16x32_bf16(a5[ks], b, acc[nt], 0, 0, 0);
            }
        }
        #pragma unroll
        for (int nt = 0; nt < 8; ++nt) {
            float bias = b1s[nt * 16 + lr];
            #pragma unroll
            for (int r = 0; r < 4; ++r) {
                float h = acc[nt][r] + bias;
                s_h1[(w * 16 + lg * 4 + r) * 136 + nt * 16 + lr] = f2bf(h > 0.f ? h : 0.f);
            }
        }
    }
    __syncthreads();

    // ---- L2: per etype, g_t = h1 @ W2t ----
    short8 a2[4];
    #pragma unroll
    for (int ks = 0; ks < 4; ++ks)
        a2[ks] = *(const short8*)&s_h1[(w * 16 + lr) * 136 + ks * 32 + lg * 8];
    for (int t = gt0; t < gt1; ++t) {
        f32x4 acc2[4];
        #pragma unroll
        for (int nt = 0; nt < 4; ++nt) acc2[nt] = (f32x4){0.f, 0.f, 0.f, 0.f};
        #pragma unroll
        for (int nt = 0; nt < 4; ++nt) {
            #pragma unroll
            for (int ks = 0; ks < 4; ++ks) {
                short8 b = *(const short8*)&w2t[((size_t)t * OUT_DIM + nt * 16 + lr) * HID_DIM + ks * 32 + lg * 8];
                acc2[nt] = __builtin_amdgcn_mfma_f32_16x16x32_bf16(a2[ks], b, acc2[nt], 0, 0, 0);
            }
        }
        __syncthreads();          // prev s_out consumers done
        #pragma unroll
        for (int nt = 0; nt < 4; ++nt)
            #pragma unroll
            for (int r = 0; r < 4; ++r)
                s_out[(w * 16 + lg * 4 + r) * 72 + nt * 16 + lr] = f2bf(acc2[nt][r]);
        __syncthreads();
        size_t pb = (size_t)(t - gt0) * N_NODES;
        #pragma unroll
        for (int j = 0; j < 4; ++j) {
            int flat = j * 256 + tid;
            int rrow = flat >> 4, c4 = (flat & 15) * 4;
            int n = base + rrow;
            if (n < N_NODES)
                *(ushort4*)&g[(pb + n) * OUT_DIM + c4] = *(const ushort4*)&s_out[rrow * 72 + c4];
        }
    }
}

// ------ layer-2 gather: 32-lane group per node (2 nodes/wave), all etypes, 4-way unroll.
// ------ kmax group-uniform => shfl always in uniform control flow within the group.
__global__ __launch_bounds__(256) void k_gather2(const int* __restrict__ rowptr,
                                                 const int* __restrict__ csr,
                                                 const u32* __restrict__ g32,
                                                 u32* __restrict__ h232) {
    int tid = threadIdx.x;
    int lane = tid & 31;
    int lanebase = tid & 32;                  // group base within the 64-lane wave
    int n = blockIdx.x * 8 + (tid >> 5);
    int kb = n * N_ETYPES;
    float acc0 = 0.f, acc1 = 0.f;
    for (int tc = 0; tc < N_ETYPES; ++tc) {
        int rp0 = rowptr[kb + tc];
        int deg = rowptr[kb + tc + 1] - rp0;
        int stage = csr[rp0 + lane];          // 32 staged entries
        int kmax = deg < 32 ? deg : 32;
        const u32* gp = g32 + (size_t)tc * N_NODES * 32;
        u32 v = gp[(size_t)n * 32 + lane];    // self
        float s0 = lo2f(v), s1 = hi2f(v);
        float s2 = 0.f, s3 = 0.f, s4 = 0.f, s5 = 0.f, s6 = 0.f, s7 = 0.f;
        int k = 0;
        for (; k + 3 < kmax; k += 4) {        // 4 rows in flight
            int p0 = __shfl(stage, lanebase + k);
            int p1 = __shfl(stage, lanebase + k + 1);
            int p2 = __shfl(stage, lanebase + k + 2);
            int p3 = __shfl(stage, lanebase + k + 3);
            u32 v0 = gp[(size_t)p0 * 32 + lane];
            u32 v1 = gp[(size_t)p1 * 32 + lane];
            u32 v2 = gp[(size_t)p2 * 32 + lane];
            u32 v3 = gp[(size_t)p3 * 32 + lane];
            s0 += lo2f(v0); s1 += hi2f(v0);
            s2 += lo2f(v1); s3 += hi2f(v1);
            s4 += lo2f(v2); s5 += hi2f(v2);
            s6 += lo2f(v3); s7 += hi2f(v3);
        }
        for (; k < kmax; ++k) {               // remainder: uniform single steps
            int p0 = __shfl(stage, lanebase + k);
            u32 v0 = gp[(size_t)p0 * 32 + lane];
            s0 += lo2f(v0); s1 += hi2f(v0);
        }
        for (; k < deg; ++k) {                // deg>32: ~never; uniform broadcast load
            int p0 = csr[rp0 + k];
            u32 v0 = gp[(size_t)p0 * 32 + lane];
            s0 += lo2f(v0); s1 += hi2f(v0);
        }
        float inv = 1.0f / (float)(deg + 1);
        acc0 = fmaf((s0 + s2) + (s4 + s6), inv, acc0);
        acc1 = fmaf((s1 + s3) + (s5 + s7), inv, acc1);
    }
    h232[(size_t)n * 32 + lane] = (u32)f2bf(acc0) | ((u32)f2bf(acc1) << 16);
}

// ---------------- pooling stage 1: chunked partial sums (sorted gids -> few atomics) -------
__global__ __launch_bounds__(256) void k_pool1(const u16* __restrict__ h2,
                                               const int* __restrict__ gids,
                                               float* __restrict__ out_acc) {
    int w = threadIdx.x >> 6, lane = threadIdx.x & 63;
    int n0 = blockIdx.x * 256 + w * 64;
    int nend = n0 + 64; if (nend > N_NODES) nend = N_NODES;
    float acc = 0.f;
    int cur = -1;
    for (int n = n0; n < nend; ++n) {
        int gid = gids[n];
        if (gid != cur) {
            if (cur >= 0) atomicAdd(&out_acc[cur * OUT_DIM + lane], acc);
            acc = 0.f; cur = gid;
        }
        acc += bf2f(h2[(size_t)n * OUT_DIM + lane]);
    }
    if (cur >= 0) atomicAdd(&out_acc[cur * OUT_DIM + lane], acc);
}

// ---------------- pooling stage 2: divide by count, add bias ----------------
__global__ __launch_bounds__(64) void k_pool2(const float* __restrict__ out_acc,
                                              const int* __restrict__ gids,
                                              const float* __restrict__ b2,
                                              float* __restrict__ out) {
    int gid = blockIdx.x, j = threadIdx.x;
    int lo = 0, hi = N_NODES;
    while (lo < hi) { int mid = (lo + hi) >> 1; if (gids[mid] < gid) lo = mid + 1; else hi = mid; }
    int start = lo;
    hi = N_NODES;
    while (lo < hi) { int mid = (lo + hi) >> 1; if (gids[mid] < gid + 1) lo = mid + 1; else hi = mid; }
    int count = lo - start;
    float b = 0.f;
    #pragma unroll
    for (int t = 0; t < N_ETYPES; ++t) b += b2[t * OUT_DIM + j];
    float c = (float)count;
    out[gid * OUT_DIM + j] = (out_acc[gid * OUT_DIM + j] + c * b) / fmaxf(c, 1.0f);
}

extern "C" void kernel_launch(void* const* d_in, const int* in_sizes, int n_in,
                              void* d_out, int out_size, void* d_ws, size_t ws_size,
                              hipStream_t stream) {
    const float* x    = (const float*)d_in[0];
    const int*   edges= (const int*)d_in[1];
    const int*   gids = (const int*)d_in[2];
    const float* W1   = (const float*)d_in[3];
    const float* b1   = (const float*)d_in[4];
    const float* W2   = (const float*)d_in[5];
    const float* b2   = (const float*)d_in[6];
    float* out = (float*)d_out;

    // word-offset (u32) workspace layout; total 31,335,296 words = 125.3 MB (audited r10)
    int*   bin_cnt = (int*)d_ws;                          // 0       (256)
    int*   rowptr  = bin_cnt + 256;                       // 256     (500,016)
    int*   csr     = bin_cnt + 500272;                    // 500,272 (4,000,080)
    u16*   xb      = (u16*)(bin_cnt + 4500352);           // 4,500,352 (1,600,000 u16 = 800,000 w)
    u16*   w1t     = (u16*)(bin_cnt + 6100352);           // 6,100,352 (20,480 u16 = 10,240 w)
    u16*   w2t     = (u16*)(bin_cnt + 6110592);           // 6,110,592 (40,960 u16 = 20,480 w)
    float* b1s     = (float*)(bin_cnt + 6131072);         // 6,131,072 (128, pad to 6,131,200)
    u16*   acat    = (u16*)(bin_cnt + 6131200);           // 6,131,200 (12,000,000 u16 = 6,000,000 w)
    u16*   g       = (u16*)(bin_cnt + 12131200);          // 12,131,200 (32,000,000 u16 = 16,000,000 w)
    int*   binned  = bin_cnt + 12131200;                  // alias over g head (4,515,840 w)
    u16*   h2      = (u16*)(bin_cnt + 28131200);          // 28,131,200 (6,400,000 u16 = 3,200,000 w)
    float* out_acc = (float*)(bin_cnt + 31331200);        // 31,331,200 (4,096)

    hipMemsetAsync(bin_cnt, 0, 256 * sizeof(int), stream);
    hipMemsetAsync(out_acc, 0, NUM_GRAPHS * OUT_DIM * sizeof(float), stream);

    k_prep<<<1024, 256, 0, stream>>>(W1, W2, b1, x, w1t, w2t, b1s, xb);
    k_bin<<<(TOT_EDGES + CHUNK - 1) / CHUNK, 256, 0, stream>>>(edges, bin_cnt, binned);
    k_csr<<<NBINS, 256, 0, stream>>>(bin_cnt, binned, rowptr, csr);

    k_gather1<<<dim3(N_NODES / 16, N_ETYPES), 256, 0, stream>>>(
        rowptr, csr, (const u32*)xb, (u32*)acat);

    int nblk = (N_NODES + 63) / 64;
    k_gemm12<<<nblk, 256, 0, stream>>>(acat, w1t, w2t, b1s, g, 0, 5);   // single pass, 5 planes
    k_gather2<<<N_NODES / 8, 256, 0, stream>>>(rowptr, csr, (const u32*)g, (u32*)h2);

    k_pool1<<<(N_NODES + 255) / 256, 256, 0, stream>>>(h2, gids, out_acc);
    k_pool2<<<NUM_GRAPHS, 64, 0, stream>>>(out_acc, gids, b2, out);
}